// Round 1
// baseline (3583.320 us; speedup 1.0000x reference)
//
#include <hip/hip_runtime.h>
#include <hip/hip_bf16.h>

#define B_   2
#define T_   2048
#define DM_  2048
#define HQ_  32
#define HKV_ 8
#define HD_  64

// ---------------------------------------------------------------------------
// Workspace layout (floats):
//   Q : B*HQ*T*HD   = 8388608   (B,HQ,T,HD)
//   K : B*HKV*T*HD  = 2097152   (B,HKV,T,HD)
//   V : B*HKV*T*HD  = 2097152   (B,HKV,T,HD)
//   O : B*T*HQ*HD   = 8388608   (B,T,HQ*HD)
// total 20971520 floats = 80 MiB
// ---------------------------------------------------------------------------

// ---------------- QKV projection GEMM ----------------
// C[m][n] = sum_k x[m][k] * W[n][k];  M=4096, N=3072 (2048 Q | 512 K | 512 V)
// 64x64 block tile, 256 threads, 4x4 micro-tile, BK=16.
// Head boundaries (2048, 2560) are multiples of 64 so each block maps to one
// uniform weight matrix and exactly one head -> direct scatter into
// (B,H,T,HD) layouts.
__global__ __launch_bounds__(256) void qkv_gemm(
    const float* __restrict__ x,
    const float* __restrict__ WQ, const float* __restrict__ WK,
    const float* __restrict__ WV,
    float* __restrict__ Qo, float* __restrict__ Ko, float* __restrict__ Vo)
{
    __shared__ float As[16][68];   // [k][m], stride 68 floats = 272B (16B mult)
    __shared__ float Bs[16][68];   // [k][n]
    const int tid = threadIdx.x;
    const int tx  = tid & 15;
    const int ty  = tid >> 4;
    const int n0  = blockIdx.x * 64;
    const int m0  = blockIdx.y * 64;

    const float* W; int nrel;
    if (n0 < 2048)      { W = WQ; nrel = n0; }
    else if (n0 < 2560) { W = WK; nrel = n0 - 2048; }
    else                { W = WV; nrel = n0 - 2560; }

    const int lrow = tid >> 2;          // 0..63
    const int lk   = (tid & 3) << 2;    // 0,4,8,12
    const float* aptr = x + (size_t)(m0 + lrow) * DM_ + lk;
    const float* bptr = W + (size_t)(nrel + lrow) * DM_ + lk;

    float c[4][4] = {};

    for (int k0 = 0; k0 < DM_; k0 += 16) {
        float4 av = *(const float4*)(aptr + k0);
        float4 bv = *(const float4*)(bptr + k0);
        As[lk+0][lrow]=av.x; As[lk+1][lrow]=av.y; As[lk+2][lrow]=av.z; As[lk+3][lrow]=av.w;
        Bs[lk+0][lrow]=bv.x; Bs[lk+1][lrow]=bv.y; Bs[lk+2][lrow]=bv.z; Bs[lk+3][lrow]=bv.w;
        __syncthreads();
        #pragma unroll
        for (int kk = 0; kk < 16; ++kk) {
            float4 a4 = *(const float4*)&As[kk][ty<<2];
            float4 b4 = *(const float4*)&Bs[kk][tx<<2];
            const float a[4]  = {a4.x,a4.y,a4.z,a4.w};
            const float bb[4] = {b4.x,b4.y,b4.z,b4.w};
            #pragma unroll
            for (int i=0;i<4;++i)
                #pragma unroll
                for (int j=0;j<4;++j)
                    c[i][j] = fmaf(a[i], bb[j], c[i][j]);
        }
        __syncthreads();
    }

    const int b  = m0 >> 11;                 // m0 / T_
    const int t0 = (m0 & 2047) + (ty << 2);  // block row base + micro row
    float* dst;
    if (n0 < 2048)      dst = Qo + (((size_t)(b*HQ_  + (n0       >> 6)))*T_ + t0)*HD_;
    else if (n0 < 2560) dst = Ko + (((size_t)(b*HKV_ + ((n0-2048)>> 6)))*T_ + t0)*HD_;
    else                dst = Vo + (((size_t)(b*HKV_ + ((n0-2560)>> 6)))*T_ + t0)*HD_;
    #pragma unroll
    for (int i=0;i<4;++i) {
        float4 vv = make_float4(c[i][0],c[i][1],c[i][2],c[i][3]);
        *(float4*)(dst + (size_t)i*HD_ + (tx<<2)) = vv;
    }
}

// ---------------- RoPE (interleaved pairs, matches reference) ----------------
__global__ __launch_bounds__(256) void rope_kernel(
    float* __restrict__ Q, float* __restrict__ K, const int* __restrict__ pos)
{
    const int NQ = B_*HQ_*T_*(HD_/2);   // 4194304
    const int NK = B_*HKV_*T_*(HD_/2);  // 1048576
    int idx = blockIdx.x*256 + threadIdx.x;
    float* base;
    int rem;
    if (idx < NQ) { base = Q; rem = idx; }
    else { rem = idx - NQ; if (rem >= NK) return; base = K; }
    const int i  = rem & 31;                 // frequency index
    const int t  = (rem >> 5) & (T_ - 1);
    const int bh = rem >> 16;                // (T_*HD_/2 = 65536)
    size_t off = (((size_t)bh)*T_ + t)*HD_ + (i<<1);
    float x1 = base[off], x2 = base[off+1];
    float p = (float)pos[t];
    // inv_freq = 10000^(-2i/64) = 2^(-log2(10000) * 2i/64)
    float inv = exp2f(-13.287712379549449f * ((float)(i<<1)) * (1.0f/64.0f));
    float ang = p * inv;
    float sn, cs;
    sincosf(ang, &sn, &cs);
    base[off]   = x1*cs - x2*sn;
    base[off+1] = x1*sn + x2*cs;
}

// ---------------- Flash attention (online softmax) ----------------
// 1 wave / block; lane owns one Q row of a 64-row Q tile.
// K/V tiles (32x64) staged in LDS, read via broadcast (conflict-free).
__global__ __launch_bounds__(64) void attn_kernel(
    const float* __restrict__ Q, const float* __restrict__ K,
    const float* __restrict__ V, float* __restrict__ O)
{
    const int lane = threadIdx.x;
    const int qt   = gridDim.x - 1 - blockIdx.x;  // reversed: longest blocks first
    const int bh   = blockIdx.y;                  // b*HQ + h
    const int b    = bh >> 5;
    const int h    = bh & 31;
    const int kvh  = h >> 2;                      // G = 4
    const int qi   = qt*64 + lane;

    __shared__ float Ks[32*68];  // row stride 68 -> conflict-free staging writes
    __shared__ float Vs[32*68];

    const float* qptr  = Q + ((size_t)bh * T_ + qi) * HD_;
    const float* kbase = K + ((size_t)(b*HKV_ + kvh)) * (size_t)T_ * HD_;
    const float* vbase = V + ((size_t)(b*HKV_ + kvh)) * (size_t)T_ * HD_;

    float q[64];
    #pragma unroll
    for (int d=0; d<64; d+=4) {
        float4 v4 = *(const float4*)(qptr + d);
        q[d]=v4.x*0.125f; q[d+1]=v4.y*0.125f; q[d+2]=v4.z*0.125f; q[d+3]=v4.w*0.125f;
    }
    float o[64];
    #pragma unroll
    for (int d=0; d<64; ++d) o[d]=0.f;
    float m_run = -1e30f, l_run = 0.f;

    const int ntiles = (qt+1)*2;  // 32-wide K tiles covering keys < (qt+1)*64
    for (int kt=0; kt<ntiles; ++kt) {
        const int k0 = kt*32;
        #pragma unroll
        for (int p=0;p<8;++p) {
            int r  = (p<<2) + (lane>>4);
            int dd = (lane&15)<<2;
            *(float4*)&Ks[r*68+dd] = *(const float4*)(kbase + (size_t)(k0+r)*HD_ + dd);
            *(float4*)&Vs[r*68+dd] = *(const float4*)(vbase + (size_t)(k0+r)*HD_ + dd);
        }
        __syncthreads();

        float s[32];
        float mnew = m_run;
        #pragma unroll
        for (int j=0;j<32;++j) {
            float acc0=0.f, acc1=0.f;
            #pragma unroll
            for (int d=0; d<64; d+=8) {
                float4 k4 = *(const float4*)&Ks[j*68+d];
                float4 k5 = *(const float4*)&Ks[j*68+d+4];
                acc0 = fmaf(q[d  ],k4.x,acc0); acc0 = fmaf(q[d+1],k4.y,acc0);
                acc0 = fmaf(q[d+2],k4.z,acc0); acc0 = fmaf(q[d+3],k4.w,acc0);
                acc1 = fmaf(q[d+4],k5.x,acc1); acc1 = fmaf(q[d+5],k5.y,acc1);
                acc1 = fmaf(q[d+6],k5.z,acc1); acc1 = fmaf(q[d+7],k5.w,acc1);
            }
            float sc = acc0 + acc1;
            sc = (k0 + j <= qi) ? sc : -1e30f;   // causal mask
            s[j] = sc;
            mnew = fmaxf(mnew, sc);
        }
        float alpha = __expf(m_run - mnew);
        m_run = mnew;
        l_run *= alpha;
        #pragma unroll
        for (int d=0;d<64;++d) o[d] *= alpha;
        float psum = 0.f;
        #pragma unroll
        for (int j=0;j<32;++j) { float pj = __expf(s[j]-mnew); s[j]=pj; psum += pj; }
        l_run += psum;
        #pragma unroll
        for (int j=0;j<32;++j) {
            float pj = s[j];
            #pragma unroll
            for (int d=0;d<64;d+=4) {
                float4 v4 = *(const float4*)&Vs[j*68+d];
                o[d  ] = fmaf(pj,v4.x,o[d  ]);
                o[d+1] = fmaf(pj,v4.y,o[d+1]);
                o[d+2] = fmaf(pj,v4.z,o[d+2]);
                o[d+3] = fmaf(pj,v4.w,o[d+3]);
            }
        }
        __syncthreads();
    }

    const float rl = 1.0f / l_run;
    float* optr = O + ((size_t)(b*T_ + qi))*(HQ_*HD_) + h*HD_;
    #pragma unroll
    for (int d=0;d<64;d+=4) {
        float4 vv = make_float4(o[d]*rl,o[d+1]*rl,o[d+2]*rl,o[d+3]*rl);
        *(float4*)(optr + d) = vv;
    }
}

// ---------------- Output projection GEMM ----------------
// C[m][n] = sum_k O[m][k] * WO[n][k];  M=4096, N=2048, K=2048
__global__ __launch_bounds__(256) void out_gemm(
    const float* __restrict__ A, const float* __restrict__ W,
    float* __restrict__ C)
{
    __shared__ float As[16][68];
    __shared__ float Bs[16][68];
    const int tid = threadIdx.x;
    const int tx  = tid & 15;
    const int ty  = tid >> 4;
    const int n0  = blockIdx.x * 64;
    const int m0  = blockIdx.y * 64;

    const int lrow = tid >> 2;
    const int lk   = (tid & 3) << 2;
    const float* aptr = A + (size_t)(m0 + lrow) * DM_ + lk;
    const float* bptr = W + (size_t)(n0 + lrow) * DM_ + lk;

    float c[4][4] = {};

    for (int k0 = 0; k0 < DM_; k0 += 16) {
        float4 av = *(const float4*)(aptr + k0);
        float4 bv = *(const float4*)(bptr + k0);
        As[lk+0][lrow]=av.x; As[lk+1][lrow]=av.y; As[lk+2][lrow]=av.z; As[lk+3][lrow]=av.w;
        Bs[lk+0][lrow]=bv.x; Bs[lk+1][lrow]=bv.y; Bs[lk+2][lrow]=bv.z; Bs[lk+3][lrow]=bv.w;
        __syncthreads();
        #pragma unroll
        for (int kk = 0; kk < 16; ++kk) {
            float4 a4 = *(const float4*)&As[kk][ty<<2];
            float4 b4 = *(const float4*)&Bs[kk][tx<<2];
            const float a[4]  = {a4.x,a4.y,a4.z,a4.w};
            const float bb[4] = {b4.x,b4.y,b4.z,b4.w};
            #pragma unroll
            for (int i=0;i<4;++i)
                #pragma unroll
                for (int j=0;j<4;++j)
                    c[i][j] = fmaf(a[i], bb[j], c[i][j]);
        }
        __syncthreads();
    }

    float* dst = C + (size_t)(m0 + (ty<<2))*DM_ + n0 + (tx<<2);
    #pragma unroll
    for (int i=0;i<4;++i) {
        float4 vv = make_float4(c[i][0],c[i][1],c[i][2],c[i][3]);
        *(float4*)(dst + (size_t)i*DM_) = vv;
    }
}

extern "C" void kernel_launch(void* const* d_in, const int* in_sizes, int n_in,
                              void* d_out, int out_size, void* d_ws, size_t ws_size,
                              hipStream_t stream) {
    const float* x   = (const float*)d_in[0];
    const int*   pos = (const int*)  d_in[1];
    const float* WQ  = (const float*)d_in[2];
    const float* WK  = (const float*)d_in[3];
    const float* WV  = (const float*)d_in[4];
    const float* WO  = (const float*)d_in[5];
    float* out = (float*)d_out;

    float* Q = (float*)d_ws;
    float* K = Q + (size_t)B_*HQ_ *T_*HD_;   // +8388608
    float* V = K + (size_t)B_*HKV_*T_*HD_;   // +2097152
    float* O = V + (size_t)B_*HKV_*T_*HD_;   // +2097152

    // 1) QKV projection
    dim3 g1(48, 64);
    qkv_gemm<<<g1, 256, 0, stream>>>(x, WQ, WK, WV, Q, K, V);

    // 2) RoPE on Q and K
    const int pairs = B_*HQ_*T_*(HD_/2) + B_*HKV_*T_*(HD_/2);  // 5242880
    rope_kernel<<<(pairs + 255)/256, 256, 0, stream>>>(Q, K, pos);

    // 3) Causal GQA flash attention
    dim3 g3(T_/64, B_*HQ_);
    attn_kernel<<<g3, 64, 0, stream>>>(Q, K, V, O);

    // 4) Output projection
    dim3 g4(DM_/64, 64);
    out_gemm<<<g4, 256, 0, stream>>>(O, WO, out);
}

// Round 2
// 1394.792 us; speedup vs baseline: 2.5691x; 2.5691x over previous
//
#include <hip/hip_runtime.h>
#include <hip/hip_bf16.h>

#define B_   2
#define T_   2048
#define DM_  2048
#define HQ_  32
#define HKV_ 8
#define HD_  64

typedef __attribute__((ext_vector_type(8))) short bf16x8;
typedef __attribute__((ext_vector_type(4))) float f32x4;

__device__ __forceinline__ unsigned short f2bf(float f) {
    unsigned int u = __float_as_uint(f);
    u = (u + 0x7fffu + ((u >> 16) & 1u)) >> 16;   // RNE
    return (unsigned short)u;
}

// ---------------------------------------------------------------------------
// Workspace (75.5 MB):
//   Qf : 8388608 f   (B,HQ,T,HD)  fp32 pre-RoPE   [aliased by O later]
//   Kf : 2097152 f   (B,HKV,T,HD) fp32 pre-RoPE
//   Vf : 2097152 f   (B,HKV,T,HD) fp32
//   Qb : 8388608 us  (B,HQ,T,HD)  bf16 RoPE'd, scaled 1/8
//   Kb : 2097152 us  (B,HKV,T,HD) bf16 RoPE'd
//   Vt : 2097152 us  (B,HKV,HD,T) bf16 transposed
//   O  = Qf alias    (B,T,HQ*HD)  fp32 attention out
// ---------------------------------------------------------------------------

// ---------------- QKV projection GEMM (fp32, unchanged) ----------------
__global__ __launch_bounds__(256) void qkv_gemm(
    const float* __restrict__ x,
    const float* __restrict__ WQ, const float* __restrict__ WK,
    const float* __restrict__ WV,
    float* __restrict__ Qo, float* __restrict__ Ko, float* __restrict__ Vo)
{
    __shared__ float As[16][68];
    __shared__ float Bs[16][68];
    const int tid = threadIdx.x;
    const int tx  = tid & 15;
    const int ty  = tid >> 4;
    const int n0  = blockIdx.x * 64;
    const int m0  = blockIdx.y * 64;

    const float* W; int nrel;
    if (n0 < 2048)      { W = WQ; nrel = n0; }
    else if (n0 < 2560) { W = WK; nrel = n0 - 2048; }
    else                { W = WV; nrel = n0 - 2560; }

    const int lrow = tid >> 2;
    const int lk   = (tid & 3) << 2;
    const float* aptr = x + (size_t)(m0 + lrow) * DM_ + lk;
    const float* bptr = W + (size_t)(nrel + lrow) * DM_ + lk;

    float c[4][4] = {};

    for (int k0 = 0; k0 < DM_; k0 += 16) {
        float4 av = *(const float4*)(aptr + k0);
        float4 bv = *(const float4*)(bptr + k0);
        As[lk+0][lrow]=av.x; As[lk+1][lrow]=av.y; As[lk+2][lrow]=av.z; As[lk+3][lrow]=av.w;
        Bs[lk+0][lrow]=bv.x; Bs[lk+1][lrow]=bv.y; Bs[lk+2][lrow]=bv.z; Bs[lk+3][lrow]=bv.w;
        __syncthreads();
        #pragma unroll
        for (int kk = 0; kk < 16; ++kk) {
            float4 a4 = *(const float4*)&As[kk][ty<<2];
            float4 b4 = *(const float4*)&Bs[kk][tx<<2];
            const float a[4]  = {a4.x,a4.y,a4.z,a4.w};
            const float bb[4] = {b4.x,b4.y,b4.z,b4.w};
            #pragma unroll
            for (int i=0;i<4;++i)
                #pragma unroll
                for (int j=0;j<4;++j)
                    c[i][j] = fmaf(a[i], bb[j], c[i][j]);
        }
        __syncthreads();
    }

    const int b  = m0 >> 11;
    const int t0 = (m0 & 2047) + (ty << 2);
    float* dst;
    if (n0 < 2048)      dst = Qo + (((size_t)(b*HQ_  + (n0       >> 6)))*T_ + t0)*HD_;
    else if (n0 < 2560) dst = Ko + (((size_t)(b*HKV_ + ((n0-2048)>> 6)))*T_ + t0)*HD_;
    else                dst = Vo + (((size_t)(b*HKV_ + ((n0-2560)>> 6)))*T_ + t0)*HD_;
    #pragma unroll
    for (int i=0;i<4;++i) {
        float4 vv = make_float4(c[i][0],c[i][1],c[i][2],c[i][3]);
        *(float4*)(dst + (size_t)i*HD_ + (tx<<2)) = vv;
    }
}

// ---------------- RoPE: fp32 in -> bf16 out (Q scaled by 1/8) ----------------
__global__ __launch_bounds__(256) void rope_bf16(
    const float* __restrict__ Qf, const float* __restrict__ Kf,
    unsigned short* __restrict__ Qb, unsigned short* __restrict__ Kb,
    const int* __restrict__ pos)
{
    const int NQ = B_*HQ_*T_*(HD_/2);
    const int NK = B_*HKV_*T_*(HD_/2);
    int idx = blockIdx.x*256 + threadIdx.x;
    const float* src; unsigned short* dst; float scale;
    int rem;
    if (idx < NQ) { src = Qf; dst = Qb; rem = idx; scale = 0.125f; }
    else { rem = idx - NQ; if (rem >= NK) return; src = Kf; dst = Kb; scale = 1.0f; }
    const int i  = rem & 31;
    const int t  = (rem >> 5) & (T_ - 1);
    const int bh = rem >> 16;
    size_t off = (((size_t)bh)*T_ + t)*HD_ + (i<<1);
    float x1 = src[off], x2 = src[off+1];
    float p = (float)pos[t];
    float inv = exp2f(-13.287712379549449f * ((float)(i<<1)) * (1.0f/64.0f));
    float ang = p * inv;
    float sn, cs;
    sincosf(ang, &sn, &cs);
    float r1 = (x1*cs - x2*sn) * scale;
    float r2 = (x1*sn + x2*cs) * scale;
    unsigned int packed = (unsigned int)f2bf(r1) | ((unsigned int)f2bf(r2) << 16);
    *(unsigned int*)(dst + off) = packed;
}

// ---------------- V transpose: fp32 (T,HD) -> bf16 (HD,T) per head ----------
__global__ __launch_bounds__(256) void vt_kernel(
    const float* __restrict__ V, unsigned short* __restrict__ Vt)
{
    __shared__ float tile[32][33];
    const int bh = blockIdx.z;
    const int t0 = blockIdx.x * 32;
    const int d0 = blockIdx.y * 32;
    const int lx = threadIdx.x & 31;
    const int ly = threadIdx.x >> 5;        // 0..7
    const float* src = V + ((size_t)bh*T_ + t0)*HD_ + d0;
    #pragma unroll
    for (int i = ly; i < 32; i += 8) tile[i][lx] = src[(size_t)i*HD_ + lx];
    __syncthreads();
    unsigned short* dst = Vt + ((size_t)(bh*HD_ + d0))*T_ + t0;
    #pragma unroll
    for (int i = ly; i < 32; i += 8) dst[(size_t)i*T_ + lx] = f2bf(tile[lx][i]);
}

// ---------------- MFMA flash attention ----------------
// Block: 4 waves x 16 q-rows = 64-row Q tile for one (b,h). K/V tiles of 64.
// S^T = K.Q^T so C-layout col (lane&15) = q  -> per-lane softmax state.
// O^T = V^T.P^T accumulated in C-layout; P^T round-trips per-wave LDS.
__global__ __launch_bounds__(256) void attn_mfma(
    const unsigned short* __restrict__ Qb, const unsigned short* __restrict__ Kb,
    const unsigned short* __restrict__ Vt, float* __restrict__ O)
{
    __shared__ unsigned short Ks[64][72];   // K rows (k), d contiguous
    __shared__ unsigned short Vs[64][72];   // V^T rows (d), k contiguous
    __shared__ unsigned short Ps[4][16][72];// per-wave P^T as [q][k]

    const int tid  = threadIdx.x;
    const int lane = tid & 63;
    const int wave = tid >> 6;
    const int q16  = lane & 15;
    const int quad = lane >> 4;
    const int qt   = gridDim.x - 1 - blockIdx.x;   // longest first
    const int bh   = blockIdx.y;                   // b*HQ + h
    const int b    = bh >> 5;
    const int h    = bh & 31;
    const int kvh  = h >> 2;
    const int qglob = qt*64 + wave*16 + q16;

    const unsigned short* kbase = Kb + ((size_t)(b*HKV_ + kvh))*T_*HD_;
    const unsigned short* vbase = Vt + ((size_t)(b*HKV_ + kvh))*(size_t)HD_*T_;

    // Q fragments: B-operand B[k=d][n=q] = Q[q][d] -> contiguous row reads
    bf16x8 qf0 = *(const bf16x8*)(Qb + ((size_t)bh*T_ + qglob)*HD_ + quad*8);
    bf16x8 qf1 = *(const bf16x8*)(Qb + ((size_t)bh*T_ + qglob)*HD_ + 32 + quad*8);

    f32x4 o[4];
    #pragma unroll
    for (int i=0;i<4;++i) { o[i][0]=0.f; o[i][1]=0.f; o[i][2]=0.f; o[i][3]=0.f; }
    float m_run = -1e30f, l_run = 0.f;

    for (int kt = 0; kt <= qt; ++kt) {
        const int k0 = kt * 64;
        __syncthreads();   // previous tile's compute done before overwrite
        #pragma unroll
        for (int p = 0; p < 2; ++p) {
            int r = (tid >> 3) + p*32;
            int d = (tid & 7) * 8;
            *(uint4*)&Ks[r][d] = *(const uint4*)(kbase + (size_t)(k0 + r)*HD_ + d);
            *(uint4*)&Vs[r][d] = *(const uint4*)(vbase + (size_t)r*T_ + k0 + d);
        }
        __syncthreads();

        // S^T tiles: D[m=k-row][n=q], A = K rows, B = Q frag
        f32x4 s[4];
        #pragma unroll
        for (int t=0;t<4;++t) { s[t][0]=0.f; s[t][1]=0.f; s[t][2]=0.f; s[t][3]=0.f; }
        #pragma unroll
        for (int t = 0; t < 4; ++t) {
            bf16x8 a0 = *(const bf16x8*)&Ks[t*16 + q16][quad*8];
            bf16x8 a1 = *(const bf16x8*)&Ks[t*16 + q16][32 + quad*8];
            s[t] = __builtin_amdgcn_mfma_f32_16x16x32_bf16(a0, qf0, s[t], 0, 0, 0);
            s[t] = __builtin_amdgcn_mfma_f32_16x16x32_bf16(a1, qf1, s[t], 0, 0, 0);
        }

        if (kt == qt) {   // diagonal: mask k > q
            #pragma unroll
            for (int t = 0; t < 4; ++t)
                #pragma unroll
                for (int r = 0; r < 4; ++r)
                    if (k0 + t*16 + quad*4 + r > qglob) s[t][r] = -1e30f;
        }

        // online softmax; q = lane&15, k spread over (quad, t, r)
        float mloc = -1e30f;
        #pragma unroll
        for (int t = 0; t < 4; ++t)
            #pragma unroll
            for (int r = 0; r < 4; ++r) mloc = fmaxf(mloc, s[t][r]);
        mloc = fmaxf(mloc, __shfl_xor(mloc, 16));
        mloc = fmaxf(mloc, __shfl_xor(mloc, 32));
        float mnew  = fmaxf(m_run, mloc);
        float alpha = __expf(m_run - mnew);
        float psum = 0.f;
        #pragma unroll
        for (int t = 0; t < 4; ++t) {
            float p0 = __expf(s[t][0]-mnew);
            float p1 = __expf(s[t][1]-mnew);
            float p2 = __expf(s[t][2]-mnew);
            float p3 = __expf(s[t][3]-mnew);
            psum += (p0+p1) + (p2+p3);
            uint2 pk;
            pk.x = (unsigned int)f2bf(p0) | ((unsigned int)f2bf(p1) << 16);
            pk.y = (unsigned int)f2bf(p2) | ((unsigned int)f2bf(p3) << 16);
            *(uint2*)&Ps[wave][q16][t*16 + quad*4] = pk;   // P^T[k][q] at [q][k]
        }
        psum += __shfl_xor(psum, 16);
        psum += __shfl_xor(psum, 32);
        l_run = l_run * alpha + psum;
        m_run = mnew;
        #pragma unroll
        for (int i = 0; i < 4; ++i) {
            o[i][0]*=alpha; o[i][1]*=alpha; o[i][2]*=alpha; o[i][3]*=alpha;
        }

        // O^T += V^T . P^T   (A = V^T rows(d), B = P^T[k][q])
        bf16x8 pb0 = *(const bf16x8*)&Ps[wave][q16][quad*8];
        bf16x8 pb1 = *(const bf16x8*)&Ps[wave][q16][32 + quad*8];
        #pragma unroll
        for (int dt = 0; dt < 4; ++dt) {
            bf16x8 v0 = *(const bf16x8*)&Vs[dt*16 + q16][quad*8];
            bf16x8 v1 = *(const bf16x8*)&Vs[dt*16 + q16][32 + quad*8];
            o[dt] = __builtin_amdgcn_mfma_f32_16x16x32_bf16(v0, pb0, o[dt], 0, 0, 0);
            o[dt] = __builtin_amdgcn_mfma_f32_16x16x32_bf16(v1, pb1, o[dt], 0, 0, 0);
        }
    }

    const float rl = 1.0f / l_run;
    float* op = O + ((size_t)(b*T_ + qglob))*(HQ_*HD_) + h*HD_;
    #pragma unroll
    for (int dt = 0; dt < 4; ++dt) {
        float4 vv = make_float4(o[dt][0]*rl, o[dt][1]*rl, o[dt][2]*rl, o[dt][3]*rl);
        *(float4*)(op + dt*16 + quad*4) = vv;   // d = dt*16 + quad*4 + r
    }
}

// ---------------- Output projection GEMM (fp32, unchanged) ----------------
__global__ __launch_bounds__(256) void out_gemm(
    const float* __restrict__ A, const float* __restrict__ W,
    float* __restrict__ C)
{
    __shared__ float As[16][68];
    __shared__ float Bs[16][68];
    const int tid = threadIdx.x;
    const int tx  = tid & 15;
    const int ty  = tid >> 4;
    const int n0  = blockIdx.x * 64;
    const int m0  = blockIdx.y * 64;

    const int lrow = tid >> 2;
    const int lk   = (tid & 3) << 2;
    const float* aptr = A + (size_t)(m0 + lrow) * DM_ + lk;
    const float* bptr = W + (size_t)(n0 + lrow) * DM_ + lk;

    float c[4][4] = {};

    for (int k0 = 0; k0 < DM_; k0 += 16) {
        float4 av = *(const float4*)(aptr + k0);
        float4 bv = *(const float4*)(bptr + k0);
        As[lk+0][lrow]=av.x; As[lk+1][lrow]=av.y; As[lk+2][lrow]=av.z; As[lk+3][lrow]=av.w;
        Bs[lk+0][lrow]=bv.x; Bs[lk+1][lrow]=bv.y; Bs[lk+2][lrow]=bv.z; Bs[lk+3][lrow]=bv.w;
        __syncthreads();
        #pragma unroll
        for (int kk = 0; kk < 16; ++kk) {
            float4 a4 = *(const float4*)&As[kk][ty<<2];
            float4 b4 = *(const float4*)&Bs[kk][tx<<2];
            const float a[4]  = {a4.x,a4.y,a4.z,a4.w};
            const float bb[4] = {b4.x,b4.y,b4.z,b4.w};
            #pragma unroll
            for (int i=0;i<4;++i)
                #pragma unroll
                for (int j=0;j<4;++j)
                    c[i][j] = fmaf(a[i], bb[j], c[i][j]);
        }
        __syncthreads();
    }

    float* dst = C + (size_t)(m0 + (ty<<2))*DM_ + n0 + (tx<<2);
    #pragma unroll
    for (int i=0;i<4;++i) {
        float4 vv = make_float4(c[i][0],c[i][1],c[i][2],c[i][3]);
        *(float4*)(dst + (size_t)i*DM_) = vv;
    }
}

extern "C" void kernel_launch(void* const* d_in, const int* in_sizes, int n_in,
                              void* d_out, int out_size, void* d_ws, size_t ws_size,
                              hipStream_t stream) {
    const float* x   = (const float*)d_in[0];
    const int*   pos = (const int*)  d_in[1];
    const float* WQ  = (const float*)d_in[2];
    const float* WK  = (const float*)d_in[3];
    const float* WV  = (const float*)d_in[4];
    const float* WO  = (const float*)d_in[5];
    float* out = (float*)d_out;

    float* Qf = (float*)d_ws;
    float* Kf = Qf + (size_t)B_*HQ_ *T_*HD_;   // +8388608
    float* Vf = Kf + (size_t)B_*HKV_*T_*HD_;   // +2097152
    unsigned short* Qb = (unsigned short*)(Vf + (size_t)B_*HKV_*T_*HD_);
    unsigned short* Kb = Qb + (size_t)B_*HQ_ *T_*HD_;
    unsigned short* Vt = Kb + (size_t)B_*HKV_*T_*HD_;
    float* O = Qf;   // alias: Qf dead once Qb is built; attn reads only Qb/Kb/Vt

    // 1) QKV projection (fp32)
    dim3 g1(48, 64);
    qkv_gemm<<<g1, 256, 0, stream>>>(x, WQ, WK, WV, Qf, Kf, Vf);

    // 2) RoPE -> bf16 (Q pre-scaled 1/8); V -> bf16 transposed
    const int pairs = B_*HQ_*T_*(HD_/2) + B_*HKV_*T_*(HD_/2);
    rope_bf16<<<(pairs + 255)/256, 256, 0, stream>>>(Qf, Kf, Qb, Kb, pos);
    dim3 gv(T_/32, HD_/32, B_*HKV_);
    vt_kernel<<<gv, 256, 0, stream>>>(Vf, Vt);

    // 3) Causal GQA flash attention (bf16 MFMA)
    dim3 g3(T_/64, B_*HQ_);
    attn_mfma<<<g3, 256, 0, stream>>>(Qb, Kb, Vt, O);

    // 4) Output projection (fp32)
    dim3 g4(DM_/64, 64);
    out_gemm<<<g4, 256, 0, stream>>>(O, WO, out);
}

// Round 3
// 445.402 us; speedup vs baseline: 8.0451x; 3.1315x over previous
//
#include <hip/hip_runtime.h>
#include <hip/hip_bf16.h>

#define B_   2
#define T_   2048
#define DM_  2048
#define HQ_  32
#define HKV_ 8
#define HD_  64

typedef __attribute__((ext_vector_type(8))) short bf16x8;
typedef __attribute__((ext_vector_type(4))) float f32x4;

__device__ __forceinline__ unsigned short f2bf(float f) {
    unsigned int u = __float_as_uint(f);
    u = (u + 0x7fffu + ((u >> 16) & 1u)) >> 16;   // RNE
    return (unsigned short)u;
}
__device__ __forceinline__ float bf2f(unsigned short h) {
    return __uint_as_float(((unsigned int)h) << 16);
}

__device__ __forceinline__ void gload16(const unsigned short* g, unsigned short* l) {
    __builtin_amdgcn_global_load_lds(
        (const __attribute__((address_space(1))) unsigned int*)g,
        (__attribute__((address_space(3))) unsigned int*)l, 16, 0, 0);
}

// ---------------------------------------------------------------------------
// Workspace (ushort elements, 76 MiB total):
//   xb  : 8388608   (4096,2048)      bf16 x
//   Wb  : 6291456   (3072,2048)      bf16 [WQ;WK;WV]
//   WOb : 4194304   (2048,2048)      bf16 WO
//   Qb  : 8388608   (B,HQ,T,HD)      bf16 Q (RoPE'd in place, scaled 1/8)
//   Kb  : 2097152   (B,HKV,T,HD)     bf16 K (RoPE'd in place)
//   Vt  : 2097152   (B,HKV,HD,T)     bf16 V transposed
//   Ob  : 8388608   (B,T,HQ*HD)      bf16 attention out
// ---------------------------------------------------------------------------

// ---------------- fp32 -> bf16 convert ----------------
__global__ __launch_bounds__(256) void f32_to_bf16(
    const float* __restrict__ src, unsigned short* __restrict__ dst, int n4)
{
    int i = blockIdx.x*256 + threadIdx.x;
    if (i >= n4) return;
    float4 v = *(const float4*)(src + (size_t)i*4);
    uint2 pk;
    pk.x = (unsigned int)f2bf(v.x) | ((unsigned int)f2bf(v.y) << 16);
    pk.y = (unsigned int)f2bf(v.z) | ((unsigned int)f2bf(v.w) << 16);
    *(uint2*)(dst + (size_t)i*4) = pk;
}

// ---------------- QKV projection: bf16 MFMA GEMM (m97 structure) ----------
// C[m][n] = sum_k xb[m][k]*Wb[n][k]; M=4096, N=3072, K=2048.
// 128x128 tile, BK=32, 4 waves 2x2, 4x4 of 16x16x32 MFMA per wave.
// Epilogue scatters bf16 into Q/K (B,H,T,HD) and V^T (B,H,HD,T).
__global__ __launch_bounds__(256) void qkv_gemm_bf16(
    const unsigned short* __restrict__ Ab, const unsigned short* __restrict__ Wb,
    unsigned short* __restrict__ Qb, unsigned short* __restrict__ Kb,
    unsigned short* __restrict__ Vt)
{
    __shared__ unsigned short As[128*32];
    __shared__ unsigned short Bs[128*32];
    const int tid  = threadIdx.x;
    const int ln   = tid & 63;
    const int wv   = tid >> 6;
    const int wm   = (wv >> 1) * 64;
    const int wn   = (wv & 1) * 64;
    const int col  = ln & 15;
    const int quad = ln >> 4;
    const int m0   = blockIdx.y * 128;
    const int n0   = blockIdx.x * 128;

    const unsigned short* aG = Ab + (size_t)(m0 + (tid>>2))*DM_ + (tid&3)*8;
    const unsigned short* bG = Wb + (size_t)(n0 + (tid>>2))*DM_ + (tid&3)*8;
    unsigned short* aL0 = &As[wv*512];
    unsigned short* aL1 = &As[wv*512 + 2048];
    unsigned short* bL0 = &Bs[wv*512];
    unsigned short* bL1 = &Bs[wv*512 + 2048];

    f32x4 acc[4][4];
    #pragma unroll
    for (int i=0;i<4;++i)
        #pragma unroll
        for (int j=0;j<4;++j) { acc[i][j][0]=0.f; acc[i][j][1]=0.f; acc[i][j][2]=0.f; acc[i][j][3]=0.f; }

    for (int k0 = 0; k0 < DM_; k0 += 32) {
        __syncthreads();
        gload16(aG + k0,               aL0);
        gload16(aG + (size_t)64*DM_ + k0, aL1);
        gload16(bG + k0,               bL0);
        gload16(bG + (size_t)64*DM_ + k0, bL1);
        __syncthreads();
        bf16x8 af[4], bfr[4];
        #pragma unroll
        for (int i=0;i<4;++i) {
            af[i]  = *(const bf16x8*)&As[(wm + i*16 + col)*32 + quad*8];
            bfr[i] = *(const bf16x8*)&Bs[(wn + i*16 + col)*32 + quad*8];
        }
        #pragma unroll
        for (int i=0;i<4;++i)
            #pragma unroll
            for (int j=0;j<4;++j)
                acc[i][j] = __builtin_amdgcn_mfma_f32_16x16x32_bf16(af[i], bfr[j], acc[i][j], 0, 0, 0);
    }

    const int b  = m0 >> 11;
    const int tb = m0 & 2047;
    #pragma unroll
    for (int j=0;j<4;++j) {
        const int n = n0 + wn + j*16 + col;
        #pragma unroll
        for (int i=0;i<4;++i) {
            const int t = tb + wm + i*16 + quad*4;
            #pragma unroll
            for (int r=0;r<4;++r) {
                unsigned short v = f2bf(acc[i][j][r]);
                if (n < 2048) {
                    Qb[(((size_t)(b*HQ_ + (n>>6)))*T_ + t + r)*HD_ + (n&63)] = v;
                } else if (n < 2560) {
                    Kb[(((size_t)(b*HKV_ + ((n-2048)>>6)))*T_ + t + r)*HD_ + (n&63)] = v;
                } else {
                    Vt[(((size_t)(b*HKV_ + ((n-2560)>>6)))*HD_ + (n&63))*T_ + t + r] = v;
                }
            }
        }
    }
}

// ---------------- RoPE in place on bf16 Q (scaled 1/8) and K ----------------
__global__ __launch_bounds__(256) void rope_inplace(
    unsigned short* __restrict__ Qb, unsigned short* __restrict__ Kb,
    const int* __restrict__ pos)
{
    const int NQ = B_*HQ_*T_*(HD_/2);
    const int NK = B_*HKV_*T_*(HD_/2);
    int idx = blockIdx.x*256 + threadIdx.x;
    unsigned short* base; float scale;
    int rem;
    if (idx < NQ) { base = Qb; rem = idx; scale = 0.125f; }
    else { rem = idx - NQ; if (rem >= NK) return; base = Kb; scale = 1.0f; }
    const int i  = rem & 31;
    const int t  = (rem >> 5) & (T_ - 1);
    const int bh = rem >> 16;
    size_t off = (((size_t)bh)*T_ + t)*HD_ + (i<<1);
    unsigned int pk = *(unsigned int*)(base + off);
    float x1 = __uint_as_float((pk & 0xffffu) << 16);
    float x2 = __uint_as_float(pk & 0xffff0000u);
    float p = (float)pos[t];
    float inv = exp2f(-13.287712379549449f * ((float)(i<<1)) * (1.0f/64.0f));
    float ang = p * inv;
    float sn, cs;
    sincosf(ang, &sn, &cs);
    float r1 = (x1*cs - x2*sn) * scale;
    float r2 = (x1*sn + x2*cs) * scale;
    unsigned int out = (unsigned int)f2bf(r1) | ((unsigned int)f2bf(r2) << 16);
    *(unsigned int*)(base + off) = out;
}

// ---------------- MFMA flash attention (writes bf16 O) ----------------
__global__ __launch_bounds__(256) void attn_mfma(
    const unsigned short* __restrict__ Qb, const unsigned short* __restrict__ Kb,
    const unsigned short* __restrict__ Vt, unsigned short* __restrict__ Ob)
{
    __shared__ unsigned short Ks[64][72];
    __shared__ unsigned short Vs[64][72];
    __shared__ unsigned short Ps[4][16][72];

    const int tid  = threadIdx.x;
    const int lane = tid & 63;
    const int wave = tid >> 6;
    const int q16  = lane & 15;
    const int quad = lane >> 4;
    const int qt   = gridDim.x - 1 - blockIdx.x;
    const int bh   = blockIdx.y;
    const int b    = bh >> 5;
    const int h    = bh & 31;
    const int kvh  = h >> 2;
    const int qglob = qt*64 + wave*16 + q16;

    const unsigned short* kbase = Kb + ((size_t)(b*HKV_ + kvh))*T_*HD_;
    const unsigned short* vbase = Vt + ((size_t)(b*HKV_ + kvh))*(size_t)HD_*T_;

    bf16x8 qf0 = *(const bf16x8*)(Qb + ((size_t)bh*T_ + qglob)*HD_ + quad*8);
    bf16x8 qf1 = *(const bf16x8*)(Qb + ((size_t)bh*T_ + qglob)*HD_ + 32 + quad*8);

    f32x4 o[4];
    #pragma unroll
    for (int i=0;i<4;++i) { o[i][0]=0.f; o[i][1]=0.f; o[i][2]=0.f; o[i][3]=0.f; }
    float m_run = -1e30f, l_run = 0.f;

    for (int kt = 0; kt <= qt; ++kt) {
        const int k0 = kt * 64;
        __syncthreads();
        #pragma unroll
        for (int p = 0; p < 2; ++p) {
            int r = (tid >> 3) + p*32;
            int d = (tid & 7) * 8;
            *(uint4*)&Ks[r][d] = *(const uint4*)(kbase + (size_t)(k0 + r)*HD_ + d);
            *(uint4*)&Vs[r][d] = *(const uint4*)(vbase + (size_t)r*T_ + k0 + d);
        }
        __syncthreads();

        f32x4 s[4];
        #pragma unroll
        for (int t=0;t<4;++t) { s[t][0]=0.f; s[t][1]=0.f; s[t][2]=0.f; s[t][3]=0.f; }
        #pragma unroll
        for (int t = 0; t < 4; ++t) {
            bf16x8 a0 = *(const bf16x8*)&Ks[t*16 + q16][quad*8];
            bf16x8 a1 = *(const bf16x8*)&Ks[t*16 + q16][32 + quad*8];
            s[t] = __builtin_amdgcn_mfma_f32_16x16x32_bf16(a0, qf0, s[t], 0, 0, 0);
            s[t] = __builtin_amdgcn_mfma_f32_16x16x32_bf16(a1, qf1, s[t], 0, 0, 0);
        }

        if (kt == qt) {
            #pragma unroll
            for (int t = 0; t < 4; ++t)
                #pragma unroll
                for (int r = 0; r < 4; ++r)
                    if (k0 + t*16 + quad*4 + r > qglob) s[t][r] = -1e30f;
        }

        float mloc = -1e30f;
        #pragma unroll
        for (int t = 0; t < 4; ++t)
            #pragma unroll
            for (int r = 0; r < 4; ++r) mloc = fmaxf(mloc, s[t][r]);
        mloc = fmaxf(mloc, __shfl_xor(mloc, 16));
        mloc = fmaxf(mloc, __shfl_xor(mloc, 32));
        float mnew  = fmaxf(m_run, mloc);
        float alpha = __expf(m_run - mnew);
        float psum = 0.f;
        #pragma unroll
        for (int t = 0; t < 4; ++t) {
            float p0 = __expf(s[t][0]-mnew);
            float p1 = __expf(s[t][1]-mnew);
            float p2 = __expf(s[t][2]-mnew);
            float p3 = __expf(s[t][3]-mnew);
            psum += (p0+p1) + (p2+p3);
            uint2 pk;
            pk.x = (unsigned int)f2bf(p0) | ((unsigned int)f2bf(p1) << 16);
            pk.y = (unsigned int)f2bf(p2) | ((unsigned int)f2bf(p3) << 16);
            *(uint2*)&Ps[wave][q16][t*16 + quad*4] = pk;
        }
        psum += __shfl_xor(psum, 16);
        psum += __shfl_xor(psum, 32);
        l_run = l_run * alpha + psum;
        m_run = mnew;
        #pragma unroll
        for (int i = 0; i < 4; ++i) {
            o[i][0]*=alpha; o[i][1]*=alpha; o[i][2]*=alpha; o[i][3]*=alpha;
        }

        bf16x8 pb0 = *(const bf16x8*)&Ps[wave][q16][quad*8];
        bf16x8 pb1 = *(const bf16x8*)&Ps[wave][q16][32 + quad*8];
        #pragma unroll
        for (int dt = 0; dt < 4; ++dt) {
            bf16x8 v0 = *(const bf16x8*)&Vs[dt*16 + q16][quad*8];
            bf16x8 v1 = *(const bf16x8*)&Vs[dt*16 + q16][32 + quad*8];
            o[dt] = __builtin_amdgcn_mfma_f32_16x16x32_bf16(v0, pb0, o[dt], 0, 0, 0);
            o[dt] = __builtin_amdgcn_mfma_f32_16x16x32_bf16(v1, pb1, o[dt], 0, 0, 0);
        }
    }

    const float rl = 1.0f / l_run;
    unsigned short* op = Ob + ((size_t)(b*T_ + qglob))*(HQ_*HD_) + h*HD_;
    #pragma unroll
    for (int dt = 0; dt < 4; ++dt) {
        uint2 pk;
        pk.x = (unsigned int)f2bf(o[dt][0]*rl) | ((unsigned int)f2bf(o[dt][1]*rl) << 16);
        pk.y = (unsigned int)f2bf(o[dt][2]*rl) | ((unsigned int)f2bf(o[dt][3]*rl) << 16);
        *(uint2*)(op + dt*16 + quad*4) = pk;
    }
}

// ---------------- Output projection: bf16 MFMA GEMM ----------------
// C[m][n] = sum_k Ob[m][k]*WOb[n][k]; M=4096, N=2048, K=2048; C fp32.
__global__ __launch_bounds__(256) void out_gemm_bf16(
    const unsigned short* __restrict__ Ab, const unsigned short* __restrict__ Wb,
    float* __restrict__ C)
{
    __shared__ unsigned short As[128*32];
    __shared__ unsigned short Bs[128*32];
    const int tid  = threadIdx.x;
    const int ln   = tid & 63;
    const int wv   = tid >> 6;
    const int wm   = (wv >> 1) * 64;
    const int wn   = (wv & 1) * 64;
    const int col  = ln & 15;
    const int quad = ln >> 4;
    const int m0   = blockIdx.y * 128;
    const int n0   = blockIdx.x * 128;

    const unsigned short* aG = Ab + (size_t)(m0 + (tid>>2))*DM_ + (tid&3)*8;
    const unsigned short* bG = Wb + (size_t)(n0 + (tid>>2))*DM_ + (tid&3)*8;
    unsigned short* aL0 = &As[wv*512];
    unsigned short* aL1 = &As[wv*512 + 2048];
    unsigned short* bL0 = &Bs[wv*512];
    unsigned short* bL1 = &Bs[wv*512 + 2048];

    f32x4 acc[4][4];
    #pragma unroll
    for (int i=0;i<4;++i)
        #pragma unroll
        for (int j=0;j<4;++j) { acc[i][j][0]=0.f; acc[i][j][1]=0.f; acc[i][j][2]=0.f; acc[i][j][3]=0.f; }

    for (int k0 = 0; k0 < DM_; k0 += 32) {
        __syncthreads();
        gload16(aG + k0,                  aL0);
        gload16(aG + (size_t)64*DM_ + k0, aL1);
        gload16(bG + k0,                  bL0);
        gload16(bG + (size_t)64*DM_ + k0, bL1);
        __syncthreads();
        bf16x8 af[4], bfr[4];
        #pragma unroll
        for (int i=0;i<4;++i) {
            af[i]  = *(const bf16x8*)&As[(wm + i*16 + col)*32 + quad*8];
            bfr[i] = *(const bf16x8*)&Bs[(wn + i*16 + col)*32 + quad*8];
        }
        #pragma unroll
        for (int i=0;i<4;++i)
            #pragma unroll
            for (int j=0;j<4;++j)
                acc[i][j] = __builtin_amdgcn_mfma_f32_16x16x32_bf16(af[i], bfr[j], acc[i][j], 0, 0, 0);
    }

    #pragma unroll
    for (int i=0;i<4;++i) {
        const int m = m0 + wm + i*16 + quad*4;
        #pragma unroll
        for (int j=0;j<4;++j) {
            const int n = n0 + wn + j*16 + col;
            #pragma unroll
            for (int r=0;r<4;++r)
                C[(size_t)(m + r)*DM_ + n] = acc[i][j][r];
        }
    }
}

extern "C" void kernel_launch(void* const* d_in, const int* in_sizes, int n_in,
                              void* d_out, int out_size, void* d_ws, size_t ws_size,
                              hipStream_t stream) {
    const float* x   = (const float*)d_in[0];
    const int*   pos = (const int*)  d_in[1];
    const float* WQ  = (const float*)d_in[2];
    const float* WK  = (const float*)d_in[3];
    const float* WV  = (const float*)d_in[4];
    const float* WO  = (const float*)d_in[5];
    float* out = (float*)d_out;

    unsigned short* xb  = (unsigned short*)d_ws;
    unsigned short* Wb  = xb  + (size_t)8388608;
    unsigned short* WOb = Wb  + (size_t)6291456;
    unsigned short* Qb  = WOb + (size_t)4194304;
    unsigned short* Kb  = Qb  + (size_t)8388608;
    unsigned short* Vt  = Kb  + (size_t)2097152;
    unsigned short* Ob  = Vt  + (size_t)2097152;

    // 0) fp32 -> bf16 converts
    f32_to_bf16<<<8192, 256, 0, stream>>>(x,  xb,            2097152);
    f32_to_bf16<<<4096, 256, 0, stream>>>(WQ, Wb,            1048576);
    f32_to_bf16<<<1024, 256, 0, stream>>>(WK, Wb + 4194304,   262144);
    f32_to_bf16<<<1024, 256, 0, stream>>>(WV, Wb + 5242880,   262144);
    f32_to_bf16<<<4096, 256, 0, stream>>>(WO, WOb,           1048576);

    // 1) QKV projection (bf16 MFMA) -> Qb/Kb pre-RoPE, Vt transposed
    dim3 g1(24, 32);
    qkv_gemm_bf16<<<g1, 256, 0, stream>>>(xb, Wb, Qb, Kb, Vt);

    // 2) RoPE in place (Q scaled 1/8)
    const int pairs = B_*HQ_*T_*(HD_/2) + B_*HKV_*T_*(HD_/2);
    rope_inplace<<<(pairs + 255)/256, 256, 0, stream>>>(Qb, Kb, pos);

    // 3) Causal GQA flash attention (bf16 MFMA) -> Ob bf16
    dim3 g3(T_/64, B_*HQ_);
    attn_mfma<<<g3, 256, 0, stream>>>(Qb, Kb, Vt, Ob);

    // 4) Output projection (bf16 MFMA) -> fp32 out
    dim3 g4(16, 32);
    out_gemm_bf16<<<g4, 256, 0, stream>>>(Ob, WOb, out);
}